// Round 7
// baseline (429.979 us; speedup 1.0000x reference)
//
#include <hip/hip_runtime.h>
#include <cstdint>
#include <cstddef>

#define E_ 8
#define D_ 1024
#define F_ 4096
#define T_ 16384
#define C_ 2048   // tokens per expert

typedef __attribute__((ext_vector_type(8))) short short8;
typedef __attribute__((ext_vector_type(4))) float f32x4;

// fp32 -> bf16 round-to-nearest-even
__device__ __forceinline__ unsigned short f2b(float f) {
  union { float f; uint32_t u; } v; v.f = f;
  uint32_t u = v.u;
  return (unsigned short)((u + 0x7FFFu + ((u >> 16) & 1u)) >> 16);
}

// tanh-approx gelu (jax.nn.gelu default approximate=True)
__device__ __forceinline__ float gelu_t(float x) {
  float u = 0.7978845608028654f * (x + 0.044715f * x * x * x);
  float e = __expf(2.0f * u);
  return 0.5f * x * (2.0f - 2.0f / (e + 1.0f));  // 0.5x(1+tanh(u))
}

__device__ __forceinline__ void gload_lds16(const void* g, void* l) {
  __builtin_amdgcn_global_load_lds(
      (__attribute__((address_space(1))) void*)g,
      (__attribute__((address_space(3))) void*)l, 16, 0, 0);
}

#define MEMFENCE() asm volatile("" ::: "memory")
#define BAR() do { MEMFENCE(); __builtin_amdgcn_s_barrier(); MEMFENCE(); } while (0)

// ---------------- pre-pass: fp32 -> bf16 elementwise ----------------
__global__ void cvt_bf16_kernel(const float* __restrict__ in,
                                unsigned short* __restrict__ out, int n) {
  int idx = blockIdx.x * blockDim.x + threadIdx.x;
  int stride = gridDim.x * blockDim.x;
  for (int i = idx * 8; i < n; i += stride * 8) {
    float4 a = *(const float4*)(in + i);
    float4 b = *(const float4*)(in + i + 4);
    union { unsigned short s[8]; int4 v; } r;
    r.s[0] = f2b(a.x); r.s[1] = f2b(a.y); r.s[2] = f2b(a.z); r.s[3] = f2b(a.w);
    r.s[4] = f2b(b.x); r.s[5] = f2b(b.y); r.s[6] = f2b(b.z); r.s[7] = f2b(b.w);
    *(int4*)(out + i) = r.v;
  }
}

// ---------------- pre-pass: per-expert transpose + convert ----------------
// in: [E][R][Cc] fp32  ->  out: [E][Cc][R] bf16
__global__ void transpose_cvt(const float* __restrict__ in,
                              unsigned short* __restrict__ out, int R, int Cc) {
  __shared__ float tile_s[32][33];
  const int e = blockIdx.y;
  const int ctiles = Cc >> 5;
  const int rt = blockIdx.x / ctiles, ct = blockIdx.x % ctiles;
  const int r0 = rt * 32, c0 = ct * 32;
  const float* ine = in + (size_t)e * R * Cc;
  unsigned short* oute = out + (size_t)e * R * Cc;
  const int tx = threadIdx.x & 31, ty = threadIdx.x >> 5;  // ty in 0..7
#pragma unroll
  for (int q = 0; q < 4; ++q)
    tile_s[ty + q * 8][tx] = ine[(size_t)(r0 + ty + q * 8) * Cc + c0 + tx];
  __syncthreads();
#pragma unroll
  for (int q = 0; q < 4; ++q) {
    float v = tile_s[tx][ty + q * 8];
    oute[(size_t)(c0 + ty + q * 8) * R + r0 + tx] = f2b(v);
  }
}

// ==== 256x256 batched bf16 GEMM, BK=32, ring-4, compiler-scheduled =======
// A: [E][Mt][Kt] bf16 row-major; B: [E][Nt][Kt] bf16 (row = output column).
// 512 thr = 8 waves (2M x 4N); per-wave 128x64 output; acc[8][4].
// LDS ring: 4 buffers x (A[256][32] + B[256][32]) bf16 = 128 KiB.
// Chunk swizzle both sides: LDS[row][slot] holds global chunk slot^((row>>2)&3).
// Per K-tile: {read fb,faY(t); stage(t+3); 16 MFMA A0 (fax in regs);
//              vmcnt(cnt); lgkmcnt(0); s_barrier; prefetch fax(t+1);
//              16 MFMA A1 (overlaps fax reads)}.
// ONE barrier per K-tile; no trailing barrier; no sched_barrier pinning —
// compiler free to interleave ds_read issue/counted-lgkm with MFMA.
template <int Mt, int Nt, int Kt, int EPI>
__global__ __launch_bounds__(512, 2)
void gemmR(const unsigned short* __restrict__ A,
           const unsigned short* __restrict__ B,
           const float* __restrict__ bias, void* __restrict__ Cout) {
  constexpr int NT = Kt / 32;
  constexpr int MB = Mt / 256, NB = Nt / 256;
  static_assert(NT >= 4, "");

  // bijective XCD swizzle (nwg % 8 == 0 for all our grids)
  const int nwg = E_ * MB * NB;
  const int bid = blockIdx.x;
  const int swzb = (bid & 7) * (nwg >> 3) + (bid >> 3);
  const int e = swzb / (MB * NB);
  const int rem = swzb % (MB * NB);
  const int mblk = rem / NB, nblk = rem % NB;

  const unsigned short* Ae = A + ((size_t)e * Mt + mblk * 256) * Kt;
  const unsigned short* Be = B + ((size_t)e * Nt + nblk * 256) * Kt;

  __shared__ unsigned short lds[65536];  // 128 KiB

  const int tid = threadIdx.x;
  const int lane = tid & 63, wave = tid >> 6;
  const int wm = wave >> 2, wn = wave & 3;  // 2 x 4 wave grid
  const int ls = lane >> 4, lr = lane & 15;

  // staging: chunk c in [0,1024): row = c>>2, slot = c&3; that slot holds
  // global chunk (c&3)^((row>>2)&3); LDS dest linear c*16B.
  const int c0 = tid, c1 = tid + 512;
  const int r0 = c0 >> 2, g0 = (c0 & 3) ^ ((r0 >> 2) & 3);
  const int r1 = c1 >> 2, g1 = (c1 & 3) ^ ((r1 >> 2) & 3);

  auto stage = [&](int t) {
    unsigned short* sA = lds + (t & 3) * 16384;
    unsigned short* sB = sA + 8192;
    const int k0 = t * 32;
    gload_lds16(Ae + (size_t)r0 * Kt + k0 + g0 * 8, sA + c0 * 8);
    gload_lds16(Ae + (size_t)r1 * Kt + k0 + g1 * 8, sA + c1 * 8);
    gload_lds16(Be + (size_t)r0 * Kt + k0 + g0 * 8, sB + c0 * 8);
    gload_lds16(Be + (size_t)r1 * Kt + k0 + g1 * 8, sB + c1 * 8);
  };

  // bias first (oldest vmem; retired by prologue vmcnt)
  const float* be = bias + (size_t)e * Nt + nblk * 256;
  float bv[4];
#pragma unroll
  for (int n = 0; n < 4; ++n) bv[n] = be[wn * 64 + n * 16 + lr];

  f32x4 acc[8][4] = {};
  const int sw4 = (lr >> 2) & 3;  // fragment read: slot = ls ^ ((row>>2)&3)

  stage(0); stage(1); stage(2);
  asm volatile("s_waitcnt vmcnt(8)" ::: "memory");  // tile 0 landed (all waves)
  BAR();

  short8 fax[4], fay[4], fb[4];
  {
    const unsigned short* sA = lds;  // buffer 0
#pragma unroll
    for (int m = 0; m < 4; ++m) {
      int row = wm * 128 + m * 16 + lr;
      fax[m] = *(const short8*)(sA + row * 32 + (ls ^ sw4) * 8);
    }
  }

  for (int t = 0; t < NT; ++t) {
    const unsigned short* sA = lds + (t & 3) * 16384;
    const unsigned short* sB = sA + 8192;
#pragma unroll
    for (int n = 0; n < 4; ++n) {
      int row = wn * 64 + n * 16 + lr;
      fb[n] = *(const short8*)(sB + row * 32 + (ls ^ sw4) * 8);
    }
#pragma unroll
    for (int m = 0; m < 4; ++m) {
      int row = wm * 128 + 64 + m * 16 + lr;
      fay[m] = *(const short8*)(sA + row * 32 + (ls ^ sw4) * 8);
    }
    if (t + 3 < NT) stage(t + 3);

    __builtin_amdgcn_s_setprio(1);
#pragma unroll
    for (int m = 0; m < 4; ++m)
#pragma unroll
      for (int n = 0; n < 4; ++n)
        acc[m][n] =
            __builtin_amdgcn_mfma_f32_16x16x32_bf16(fax[m], fb[n], acc[m][n], 0, 0, 0);
    __builtin_amdgcn_s_setprio(0);

    if (t + 1 < NT) {
      // counted vmem wait: retire tile t+1's staging (oldest in queue)
      if (t + 3 < NT)      asm volatile("s_waitcnt vmcnt(8)" ::: "memory");
      else if (t + 2 < NT) asm volatile("s_waitcnt vmcnt(4)" ::: "memory");
      else                 asm volatile("s_waitcnt vmcnt(0)" ::: "memory");
      asm volatile("s_waitcnt lgkmcnt(0)" ::: "memory");  // all own reads retired
      BAR();  // rendezvous: tile t+1 readable; buf (t-1)&3 reads done CU-wide
      const unsigned short* sA2 = lds + ((t + 1) & 3) * 16384;
#pragma unroll
      for (int m = 0; m < 4; ++m) {
        int row = wm * 128 + m * 16 + lr;
        fax[m] = *(const short8*)(sA2 + row * 32 + (ls ^ sw4) * 8);  // ∥ MFMA A1
      }
    }

    __builtin_amdgcn_s_setprio(1);
#pragma unroll
    for (int m = 0; m < 4; ++m)
#pragma unroll
      for (int n = 0; n < 4; ++n)
        acc[4 + m][n] =
            __builtin_amdgcn_mfma_f32_16x16x32_bf16(fay[m], fb[n], acc[4 + m][n], 0, 0, 0);
    __builtin_amdgcn_s_setprio(0);
  }

  asm volatile("s_waitcnt vmcnt(0)" ::: "memory");
  BAR();  // LDS free for epilogue reuse

  if constexpr (EPI == 1) {
    // bounce: lds as [256][256] ushort, 16B-chunk XOR swizzle (ch ^= row&7)
#pragma unroll
    for (int m = 0; m < 8; ++m)
#pragma unroll
      for (int n = 0; n < 4; ++n)
#pragma unroll
        for (int i = 0; i < 4; ++i) {
          int row = wm * 128 + m * 16 + ls * 4 + i;
          int col = wn * 64 + n * 16 + lr;
          lds[row * 256 + (((col >> 3) ^ (row & 7)) << 3) + (col & 7)] =
              f2b(gelu_t(acc[m][n][i] + bv[n]));
        }
    BAR();
    unsigned short* H = (unsigned short*)Cout;
#pragma unroll
    for (int j = 0; j < 16; ++j) {
      int row = j * 16 + wave * 2 + (lane >> 5);
      int chk = lane & 31;
      int sc = chk ^ (row & 7);
      unsigned short* dst =
          H + ((size_t)e * Mt + mblk * 256 + row) * Nt + nblk * 256 + chk * 8;
      *(int4*)dst = *(const int4*)(lds + row * 256 + sc * 8);
    }
  } else {
    float* O = (float*)Cout;
#pragma unroll
    for (int m = 0; m < 8; ++m)
#pragma unroll
      for (int n = 0; n < 4; ++n)
#pragma unroll
        for (int i = 0; i < 4; ++i) {
          int row = wm * 128 + m * 16 + ls * 4 + i;
          int col = wn * 64 + n * 16 + lr;
          O[((size_t)e * Mt + mblk * 256 + row) * Nt + nblk * 256 + col] =
              acc[m][n][i] + bv[n];
        }
  }
}

extern "C" void kernel_launch(void* const* d_in, const int* in_sizes, int n_in,
                              void* d_out, int out_size, void* d_ws, size_t ws_size,
                              hipStream_t stream) {
  const float* x = (const float*)d_in[0];
  const float* w1 = (const float*)d_in[1];
  const float* b1 = (const float*)d_in[2];
  const float* w2 = (const float*)d_in[3];
  const float* b2 = (const float*)d_in[4];
  float* out = (float*)d_out;

  unsigned short* ws = (unsigned short*)d_ws;
  unsigned short* xb = ws;                               // [T][D] bf16
  unsigned short* w1t = xb + (size_t)T_ * D_;            // [E][F][D] bf16
  unsigned short* w2t = w1t + (size_t)E_ * F_ * D_;      // [E][D][F] bf16
  unsigned short* h = w2t + (size_t)E_ * D_ * F_;        // [T][F] bf16

  cvt_bf16_kernel<<<2048, 256, 0, stream>>>(x, xb, T_ * D_);
  transpose_cvt<<<dim3((D_ / 32) * (F_ / 32), E_), 256, 0, stream>>>(w1, w1t, D_, F_);
  transpose_cvt<<<dim3((F_ / 32) * (D_ / 32), E_), 256, 0, stream>>>(w2, w2t, F_, D_);

  gemmR<C_, F_, D_, 1>
      <<<E_ * (C_ / 256) * (F_ / 256), 512, 0, stream>>>(xb, w1t, b1, h);
  gemmR<C_, D_, F_, 2>
      <<<E_ * (C_ / 256) * (D_ / 256), 512, 0, stream>>>(h, w2t, b2, out);
}

// Round 8
// 418.941 us; speedup vs baseline: 1.0263x; 1.0263x over previous
//
#include <hip/hip_runtime.h>
#include <cstdint>
#include <cstddef>

#define E_ 8
#define D_ 1024
#define F_ 4096
#define T_ 16384
#define C_ 2048   // tokens per expert

typedef __attribute__((ext_vector_type(8))) short short8;
typedef __attribute__((ext_vector_type(4))) float f32x4;

// fp32 -> bf16 round-to-nearest-even
__device__ __forceinline__ unsigned short f2b(float f) {
  union { float f; uint32_t u; } v; v.f = f;
  uint32_t u = v.u;
  return (unsigned short)((u + 0x7FFFu + ((u >> 16) & 1u)) >> 16);
}

// tanh-approx gelu (jax.nn.gelu default approximate=True)
__device__ __forceinline__ float gelu_t(float x) {
  float u = 0.7978845608028654f * (x + 0.044715f * x * x * x);
  float e = __expf(2.0f * u);
  return 0.5f * x * (2.0f - 2.0f / (e + 1.0f));  // 0.5x(1+tanh(u))
}

__device__ __forceinline__ void gload_lds16(const void* g, void* l) {
  __builtin_amdgcn_global_load_lds(
      (__attribute__((address_space(1))) void*)g,
      (__attribute__((address_space(3))) void*)l, 16, 0, 0);
}

// ---------------- pre-pass: fp32 -> bf16 elementwise ----------------
__global__ void cvt_bf16_kernel(const float* __restrict__ in,
                                unsigned short* __restrict__ out, int n) {
  int idx = blockIdx.x * blockDim.x + threadIdx.x;
  int stride = gridDim.x * blockDim.x;
  for (int i = idx * 8; i < n; i += stride * 8) {
    float4 a = *(const float4*)(in + i);
    float4 b = *(const float4*)(in + i + 4);
    union { unsigned short s[8]; int4 v; } r;
    r.s[0] = f2b(a.x); r.s[1] = f2b(a.y); r.s[2] = f2b(a.z); r.s[3] = f2b(a.w);
    r.s[4] = f2b(b.x); r.s[5] = f2b(b.y); r.s[6] = f2b(b.z); r.s[7] = f2b(b.w);
    *(int4*)(out + i) = r.v;
  }
}

// ---------------- pre-pass: per-expert transpose + convert ----------------
// in: [E][R][Cc] fp32  ->  out: [E][Cc][R] bf16
__global__ void transpose_cvt(const float* __restrict__ in,
                              unsigned short* __restrict__ out, int R, int Cc) {
  __shared__ float tile_s[32][33];
  const int e = blockIdx.y;
  const int ctiles = Cc >> 5;
  const int rt = blockIdx.x / ctiles, ct = blockIdx.x % ctiles;
  const int r0 = rt * 32, c0 = ct * 32;
  const float* ine = in + (size_t)e * R * Cc;
  unsigned short* oute = out + (size_t)e * R * Cc;
  const int tx = threadIdx.x & 31, ty = threadIdx.x >> 5;  // ty in 0..7
#pragma unroll
  for (int q = 0; q < 4; ++q)
    tile_s[ty + q * 8][tx] = ine[(size_t)(r0 + ty + q * 8) * Cc + c0 + tx];
  __syncthreads();
#pragma unroll
  for (int q = 0; q < 4; ++q) {
    float v = tile_s[tx][ty + q * 8];
    oute[(size_t)(c0 + ty + q * 8) * R + r0 + tx] = f2b(v);
  }
}

// ======== 256x256 batched bf16 GEMM — m201 8-phase, UNPINNED =============
// Identical to the r5 port EXCEPT: zero sched_barrier(0) in the hot loop —
// compiler free to interleave ds_read issue / counted-lgkm with MFMA (m141).
// A: [E][Mt][Kt] bf16 row-major; B: [E][Nt][Kt] bf16 (row = output column).
// 512 thr = 8 waves (2Mx4N per 128x128 quadrant; per-wave 64x32 per phase).
// K-tile = 64. LDS half-tiles [128 rows][64 k] bf16 (16 KiB each):
//   slots (parity p, id): A0,A1,B0,B1 -> (p*4+id)*8192 shorts; +16 KiB pad.
// Per-row 8-chunk XOR swizzle: LDS[row][slot] holds global chunk slot^(row&7).
// Phase = {12 ds_read_b128, stage 1 half (2 gload_lds), [vmcnt(4) @P4,P8],
//          s_barrier, lgkmcnt(0), setprio, 16 MFMA, setprio, s_barrier}.
template <int Mt, int Nt, int Kt, int EPI>
__global__ __launch_bounds__(512, 2)
void gemm8u(const unsigned short* __restrict__ A,
            const unsigned short* __restrict__ B,
            const float* __restrict__ bias, void* __restrict__ Cout) {
  constexpr int NT = Kt / 64;       // K-tiles
  constexpr int NI = NT / 2;        // iterations
  constexpr int MB = Mt / 256, NB = Nt / 256;
  static_assert(NT >= 4 && (NT % 2) == 0, "");

  // bijective XCD swizzle (nwg % 8 == 0 for all our grids)
  const int nwg = E_ * MB * NB;
  const int bid = blockIdx.x;
  const int swzb = (bid & 7) * (nwg >> 3) + (bid >> 3);
  const int e = swzb / (MB * NB);
  const int rem = swzb % (MB * NB);
  const int mblk = rem / NB, nblk = rem % NB;

  const unsigned short* Ae = A + ((size_t)e * Mt + mblk * 256) * Kt;
  const unsigned short* Be = B + ((size_t)e * Nt + nblk * 256) * Kt;

  __shared__ unsigned short lds[73728];  // 144 KiB (8 half-slots + pad)

  const int tid = threadIdx.x;
  const int lane = tid & 63, wave = tid >> 6;
  const int wm = wave >> 2, wn = wave & 3;  // 2 x 4 within each quadrant
  const int ls = lane >> 4, lr = lane & 15;

  // staging: chunk c in [0,1024) of a half-tile: row=c>>3, slot=c&7,
  // global chunk g = (c&7)^(row&7); LDS dest linear c*16B (both-sides swz).
  const int c0 = tid, c1 = tid + 512;
  const int r0c = c0 >> 3, g0c = (c0 & 7) ^ (r0c & 7);
  const int r1c = c1 >> 3, g1c = (c1 & 7) ^ (r1c & 7);

  auto stA = [&](int rh, int p, int t, bool valid) {
    unsigned short* dst = valid ? (lds + (size_t)(p * 4 + rh) * 8192)
                                : (lds + 65536);
    const int tt = valid ? t : NT - 1;
    const unsigned short* s = Ae + (size_t)rh * 128 * Kt + tt * 64;
    gload_lds16(s + (size_t)r0c * Kt + g0c * 8, dst + c0 * 8);
    gload_lds16(s + (size_t)r1c * Kt + g1c * 8, dst + c1 * 8);
  };
  auto stB = [&](int ch, int p, int t, bool valid) {
    unsigned short* dst = valid ? (lds + (size_t)(p * 4 + 2 + ch) * 8192)
                                : (lds + 65536);
    const int tt = valid ? t : NT - 1;
    const unsigned short* s = Be + (size_t)ch * 128 * Kt + tt * 64;
    gload_lds16(s + (size_t)r0c * Kt + g0c * 8, dst + c0 * 8);
    gload_lds16(s + (size_t)r1c * Kt + g1c * 8, dst + c1 * 8);
  };

  f32x4 acc[2][2][4][2] = {};  // [rh][ch][m][n]

  // bias fragments first (oldest vmem, drained by prologue vmcnt)
  const float* be = bias + (size_t)e * Nt + nblk * 256;
  float bvf[2][2];
#pragma unroll
  for (int ch = 0; ch < 2; ++ch)
#pragma unroll
    for (int n = 0; n < 2; ++n)
      bvf[ch][n] = be[ch * 128 + wn * 32 + n * 16 + lr];

  // prologue: virtual P3..P8 of iteration -1
  stA(0, 0, 0, true); stB(1, 0, 0, true); stA(1, 0, 0, true);
  stB(0, 0, 0, true); stA(0, 1, 1, true); stB(1, 1, 1, true);
  asm volatile("s_waitcnt vmcnt(4)" ::: "memory");  // tile0 halves landed
  __builtin_amdgcn_s_barrier();

#define PHASE(SLOT, RH, CH, STAGE_EXPR, DO_VM)                                 \
  {                                                                            \
    const unsigned short* sA = lds + (size_t)((SLOT) * 4 + (RH)) * 8192;       \
    const unsigned short* sB = lds + (size_t)((SLOT) * 4 + 2 + (CH)) * 8192;   \
    short8 fa[4][2], fb[2][2];                                                 \
    _Pragma("unroll") for (int m = 0; m < 4; ++m)                              \
      _Pragma("unroll") for (int kk = 0; kk < 2; ++kk) {                       \
        int row = wm * 64 + m * 16 + lr;                                       \
        fa[m][kk] = *(const short8*)(sA + row * 64 +                           \
                                     (((kk << 2) | ls) ^ (row & 7)) * 8);      \
      }                                                                        \
    _Pragma("unroll") for (int n = 0; n < 2; ++n)                              \
      _Pragma("unroll") for (int kk = 0; kk < 2; ++kk) {                       \
        int row = wn * 32 + n * 16 + lr;                                       \
        fb[n][kk] = *(const short8*)(sB + row * 64 +                           \
                                     (((kk << 2) | ls) ^ (row & 7)) * 8);      \
      }                                                                        \
    STAGE_EXPR;                                                                \
    if (DO_VM) asm volatile("s_waitcnt vmcnt(4)" ::: "memory");                \
    __builtin_amdgcn_s_barrier();                                              \
    asm volatile("s_waitcnt lgkmcnt(0)" ::: "memory");                         \
    __builtin_amdgcn_s_setprio(1);                                             \
    _Pragma("unroll") for (int m = 0; m < 4; ++m)                              \
      _Pragma("unroll") for (int n = 0; n < 2; ++n)                            \
        _Pragma("unroll") for (int kk = 0; kk < 2; ++kk)                       \
          acc[RH][CH][m][n] = __builtin_amdgcn_mfma_f32_16x16x32_bf16(         \
              fa[m][kk], fb[n][kk], acc[RH][CH][m][n], 0, 0, 0);               \
    __builtin_amdgcn_s_setprio(0);                                             \
    __builtin_amdgcn_s_barrier();                                              \
  }

  for (int i = 0; i < NI; ++i) {
    const int t1 = 2 * i + 1, t2 = 2 * i + 2, t3 = 2 * i + 3;
    PHASE(0, 0, 0, (stA(1, 1, t1, true)), 0)         // P1
    PHASE(0, 0, 1, (stB(0, 1, t1, true)), 0)         // P2
    PHASE(0, 1, 1, (stA(0, 0, t2, t2 < NT)), 0)      // P3
    PHASE(0, 1, 0, (stB(1, 0, t2, t2 < NT)), 1)      // P4 + vmcnt
    PHASE(1, 0, 0, (stA(1, 0, t2, t2 < NT)), 0)      // P5
    PHASE(1, 0, 1, (stB(0, 0, t2, t2 < NT)), 0)      // P6
    PHASE(1, 1, 1, (stA(0, 1, t3, t3 < NT)), 0)      // P7
    PHASE(1, 1, 0, (stB(1, 1, t3, t3 < NT)), 1)      // P8 + vmcnt
  }
#undef PHASE

  // drain all staging before LDS reuse / exit
  asm volatile("s_waitcnt vmcnt(0)" ::: "memory");
  __builtin_amdgcn_s_barrier();

  if constexpr (EPI == 1) {
    // bounce: lds as [256][256] ushort, 16B-chunk XOR swizzle (ch ^= row&7)
#pragma unroll
    for (int rh = 0; rh < 2; ++rh)
#pragma unroll
      for (int ch = 0; ch < 2; ++ch)
#pragma unroll
        for (int m = 0; m < 4; ++m)
#pragma unroll
          for (int n = 0; n < 2; ++n)
#pragma unroll
            for (int i = 0; i < 4; ++i) {
              int row = rh * 128 + wm * 64 + m * 16 + ls * 4 + i;
              int col = ch * 128 + wn * 32 + n * 16 + lr;
              lds[row * 256 + (((col >> 3) ^ (row & 7)) << 3) + (col & 7)] =
                  f2b(gelu_t(acc[rh][ch][m][n][i] + bvf[ch][n]));
            }
    __builtin_amdgcn_s_barrier();
    unsigned short* H = (unsigned short*)Cout;
#pragma unroll
    for (int j = 0; j < 16; ++j) {
      int row = j * 16 + wave * 2 + (lane >> 5);
      int chk = lane & 31;
      int sc = chk ^ (row & 7);
      unsigned short* dst =
          H + ((size_t)e * Mt + mblk * 256 + row) * Nt + nblk * 256 + chk * 8;
      *(int4*)dst = *(const int4*)(lds + row * 256 + sc * 8);
    }
  } else {
    float* O = (float*)Cout;
#pragma unroll
    for (int rh = 0; rh < 2; ++rh)
#pragma unroll
      for (int ch = 0; ch < 2; ++ch)
#pragma unroll
        for (int m = 0; m < 4; ++m)
#pragma unroll
          for (int n = 0; n < 2; ++n)
#pragma unroll
            for (int i = 0; i < 4; ++i) {
              int row = rh * 128 + wm * 64 + m * 16 + ls * 4 + i;
              int col = ch * 128 + wn * 32 + n * 16 + lr;
              O[((size_t)e * Mt + mblk * 256 + row) * Nt + nblk * 256 + col] =
                  acc[rh][ch][m][n][i] + bvf[ch][n];
            }
  }
}

extern "C" void kernel_launch(void* const* d_in, const int* in_sizes, int n_in,
                              void* d_out, int out_size, void* d_ws, size_t ws_size,
                              hipStream_t stream) {
  const float* x = (const float*)d_in[0];
  const float* w1 = (const float*)d_in[1];
  const float* b1 = (const float*)d_in[2];
  const float* w2 = (const float*)d_in[3];
  const float* b2 = (const float*)d_in[4];
  float* out = (float*)d_out;

  unsigned short* ws = (unsigned short*)d_ws;
  unsigned short* xb = ws;                               // [T][D] bf16
  unsigned short* w1t = xb + (size_t)T_ * D_;            // [E][F][D] bf16
  unsigned short* w2t = w1t + (size_t)E_ * F_ * D_;      // [E][D][F] bf16
  unsigned short* h = w2t + (size_t)E_ * D_ * F_;        // [T][F] bf16

  cvt_bf16_kernel<<<2048, 256, 0, stream>>>(x, xb, T_ * D_);
  transpose_cvt<<<dim3((D_ / 32) * (F_ / 32), E_), 256, 0, stream>>>(w1, w1t, D_, F_);
  transpose_cvt<<<dim3((F_ / 32) * (D_ / 32), E_), 256, 0, stream>>>(w2, w2t, F_, D_);

  gemm8u<C_, F_, D_, 1>
      <<<E_ * (C_ / 256) * (F_ / 256), 512, 0, stream>>>(xb, w1t, b1, h);
  gemm8u<C_, D_, F_, 2>
      <<<E_ * (C_ / 256) * (D_ / 256), 512, 0, stream>>>(h, w2t, b2, out);
}